// Round 13
// baseline (196.783 us; speedup 1.0000x reference)
//
#include <hip/hip_runtime.h>
#include <math.h>

#define Bb 8
#define Tt 256
#define MEL 128
#define Dd 192
#define NCc 20
#define ND 4                  // delta ranks (updates at t%64==0)
#define NT 32                 // theta ranks (updates at t%8==0)
#define ETAc 0.9f
#define LRc 0.1f
#define MDEC 0.99f            // 1 - ALPHA
#define EPSc 1e-5f
#define PT 2                  // pipeline rows per block (best measured structure)
#define PTILES 128            // Tt/PT
#define RTT 2                 // retrieve rows per block
#define PADD 196              // padded LDS row (196%4==0, 196%32==4 -> <=4-way)

__device__ __forceinline__ float sigmoidf_(float x) {
    return 1.0f / (1.0f + __expf(-x));
}

// coefficient of (k_i err_i^T) in M_n, valid for i<=n
__device__ __forceinline__ float memcoef(int n, int i) {
    float m = LRc, pw = LRc;
    for (int nn = i + 1; nn <= n; nn++) { pw *= ETAc; m = MDEC * m + pw; }
    return m;
}

__device__ __forceinline__ float dot4(float4 a, float4 b) {
    return a.x * b.x + a.y * b.y + a.z * b.z + a.w * b.w;
}

// ---------------------------------------------------------------------------
// prep: grid 226 x 192 — everything parallel & coalesced.
//  [0,96)    Wavo rows 2m,2m+1 = Wv_a[m,:] @ Wo_a  (R13: 4->2 rows/block,
//            halves the serial weight-load chain in prep's heaviest role)
//  [96]      b_avo = bv_a @ Wo_a + bo_a
//  [97,145)  WqtT transpose (4 rows each)
//  [145,193) WqdT transpose (4 rows each)
//  [193,225) delta k/v for (b,i): xp -> k,v   (32 blocks)
//  [225]     zero pooled
// ---------------------------------------------------------------------------
__global__ __launch_bounds__(192) void prep(
    const float* __restrict__ Wv_a, const float* __restrict__ Wo_a,
    const float* __restrict__ bv_a, const float* __restrict__ bo_a,
    const float* __restrict__ Wq_t, const float* __restrict__ Wq_d,
    const float* __restrict__ x, const float* __restrict__ W_in,
    const float* __restrict__ b_in, const float* __restrict__ Wk_d,
    const float* __restrict__ Wv_d,
    float* __restrict__ Wavo_ws, float* __restrict__ b_avo,
    float* __restrict__ WqtT, float* __restrict__ WqdT,
    float* __restrict__ Kd_ws, float* __restrict__ Vd_ws,
    float* __restrict__ pooled)
{
    __shared__ __align__(16) float smem[768];
    int blk = blockIdx.x, tid = threadIdx.x;

    if (blk < 96) {                               // Wavo: 2 rows per block
        int m0 = blk * 2;
        for (int q = tid; q < 2 * Dd; q += 192) smem[q] = Wv_a[m0 * Dd + q];
        __syncthreads();
        int o = tid;
        float a0 = 0.f, a1 = 0.f;
        #pragma unroll 4
        for (int k = 0; k < Dd; k += 2) {
            float w0 = Wo_a[(k + 0) * Dd + o], w1 = Wo_a[(k + 1) * Dd + o];
            a0 += w0 * smem[0 * Dd + k] + w1 * smem[0 * Dd + k + 1];
            a1 += w0 * smem[1 * Dd + k] + w1 * smem[1 * Dd + k + 1];
        }
        Wavo_ws[(m0 + 0) * Dd + o] = a0;
        Wavo_ws[(m0 + 1) * Dd + o] = a1;
        return;
    }
    if (blk == 96) {                              // b_avo
        int o = tid;
        float s = bo_a[o];
        #pragma unroll 4
        for (int m = 0; m < Dd; m++) s += bv_a[m] * Wo_a[m * Dd + o];
        b_avo[o] = s;
        return;
    }
    if (blk < 145) {                              // WqtT[e][o] = Wq_t[o][e]
        int r0 = 4 * (blk - 97);
        float4 v;
        v.x = Wq_t[(r0 + 0) * Dd + tid];
        v.y = Wq_t[(r0 + 1) * Dd + tid];
        v.z = Wq_t[(r0 + 2) * Dd + tid];
        v.w = Wq_t[(r0 + 3) * Dd + tid];
        *(float4*)&WqtT[tid * Dd + r0] = v;
        return;
    }
    if (blk < 193) {                              // WqdT[e][o] = Wq_d[o][e]
        int r0 = 4 * (blk - 145);
        float4 v;
        v.x = Wq_d[(r0 + 0) * Dd + tid];
        v.y = Wq_d[(r0 + 1) * Dd + tid];
        v.z = Wq_d[(r0 + 2) * Dd + tid];
        v.w = Wq_d[(r0 + 3) * Dd + tid];
        *(float4*)&WqdT[tid * Dd + r0] = v;
        return;
    }
    if (blk == 225) {                             // zero pooled
        for (int q = tid; q < Bb * Dd; q += 192) pooled[q] = 0.f;
        return;
    }

    // ---- delta k/v for (b,i) ----
    int q = blk - 193;
    int b = q >> 2, i = q & 3;
    float* XR = smem;              // [128]
    float* XP = smem + 128;        // [192]
    if (tid < 128) XR[tid] = x[((size_t)b * Tt + 64 * i) * MEL + tid];
    __syncthreads();
    {
        int o = tid;
        float acc = b_in[o];
        #pragma unroll 8
        for (int k = 0; k < MEL; k += 4) {
            acc += W_in[(k + 0) * Dd + o] * XR[k + 0];
            acc += W_in[(k + 1) * Dd + o] * XR[k + 1];
            acc += W_in[(k + 2) * Dd + o] * XR[k + 2];
            acc += W_in[(k + 3) * Dd + o] * XR[k + 3];
        }
        XP[o] = acc;
    }
    __syncthreads();
    {
        int o = tid;
        float ak = 0.f, av = 0.f;
        #pragma unroll 4
        for (int k = 0; k < Dd; k += 4) {
            float x0 = XP[k + 0], x1 = XP[k + 1], x2 = XP[k + 2], x3 = XP[k + 3];
            ak += Wk_d[(k + 0) * Dd + o] * x0 + Wk_d[(k + 1) * Dd + o] * x1
                + Wk_d[(k + 2) * Dd + o] * x2 + Wk_d[(k + 3) * Dd + o] * x3;
            av += Wv_d[(k + 0) * Dd + o] * x0 + Wv_d[(k + 1) * Dd + o] * x1
                + Wv_d[(k + 2) * Dd + o] * x2 + Wv_d[(k + 3) * Dd + o] * x3;
        }
        Kd_ws[(b * ND + i) * Dd + o] = ak;
        Vd_ws[(b * ND + i) * Dd + o] = av;
    }
}

// ---------------------------------------------------------------------------
// delta_solve: grid 88.
//  blk <40: delta roles (solve + u-projections, verified R9 body).
//  blk >=40: WqkT rows 4m..4m+3 — WqkT[d][o] = sum_e Wk_t[d][e] * Wq_t[o][e]
//  (R13, numerics verified in R10: lets the pipeline theta tail compute u
//  directly from x3 with no mid-tail barrier / KS round-trip).
// ---------------------------------------------------------------------------
__global__ __launch_bounds__(192) void delta_solve(
    const float* __restrict__ WqdT, const float* __restrict__ Kd_ws,
    float* __restrict__ Vd_ws, float* __restrict__ Ud_ws,
    const float* __restrict__ Wk_t, const float* __restrict__ WqtT,
    float* __restrict__ WqkT)
{
    int blk = blockIdx.x, tid = threadIdx.x;
    if (blk >= 40) {                              // WqkT: 4 rows per block
        __shared__ __align__(16) float RK[4 * Dd];
        int d0 = 4 * (blk - 40);
        for (int q = tid; q < 4 * Dd; q += 192) RK[q] = Wk_t[d0 * Dd + q];
        __syncthreads();
        int o = tid;
        float a0 = 0.f, a1 = 0.f, a2 = 0.f, a3 = 0.f;
        #pragma unroll 4
        for (int k = 0; k < Dd; k += 2) {
            float w0 = WqtT[(k + 0) * Dd + o], w1 = WqtT[(k + 1) * Dd + o];
            a0 += w0 * RK[0 * Dd + k] + w1 * RK[0 * Dd + k + 1];
            a1 += w0 * RK[1 * Dd + k] + w1 * RK[1 * Dd + k + 1];
            a2 += w0 * RK[2 * Dd + k] + w1 * RK[2 * Dd + k + 1];
            a3 += w0 * RK[3 * Dd + k] + w1 * RK[3 * Dd + k + 1];
        }
        WqkT[(d0 + 0) * Dd + o] = a0;
        WqkT[(d0 + 1) * Dd + o] = a1;
        WqkT[(d0 + 2) * Dd + o] = a2;
        WqkT[(d0 + 3) * Dd + o] = a3;
        return;
    }
    int b = blk / 5, role = blk % 5;
    if (role == 0) {
        __shared__ __align__(16) float K4[ND][Dd], V4[ND][Dd];
        __shared__ float G[16], mc[16];
        for (int q = tid; q < ND * 48; q += 192) {
            int i = q / 48, c = q - i * 48;
            ((float4*)K4[i])[c] = ((const float4*)&Kd_ws[(b * ND + i) * Dd])[c];
            ((float4*)V4[i])[c] = ((const float4*)&Vd_ws[(b * ND + i) * Dd])[c];
        }
        __syncthreads();
        if (tid < 128) {                       // pair p = tid>>3, lane c = tid&7
            int p = tid >> 3, c = tid & 7;
            int i = p >> 2, j = p & 3;
            float s = 0.f;
            #pragma unroll
            for (int d = c * 24; d < c * 24 + 24; d++) s += K4[i][d] * K4[j][d];
            s += __shfl_down(s, 4, 8);
            s += __shfl_down(s, 2, 8);
            s += __shfl_down(s, 1, 8);
            if (c == 0) G[p] = s;
        }
        if (tid < 16) {
            int i = tid >> 2, j = tid & 3;
            mc[tid] = (j <= i) ? memcoef(i, j) : 0.f;   // mc[n=i][i=j]
        }
        __syncthreads();
        for (int i = 1; i < ND; i++) {
            float acc = V4[i][tid];
            for (int m = 0; m < i; m++)
                acc -= mc[(i - 1) * ND + m] * G[i * ND + m] * V4[m][tid];
            V4[i][tid] = acc;        // writes row i; others read rows < i only
            __syncthreads();
        }
        for (int i = 0; i < ND; i++) Vd_ws[(b * ND + i) * Dd + tid] = V4[i][tid];
    } else {
        __shared__ float KS[Dd];
        int i = role - 1;
        KS[tid] = Kd_ws[(b * ND + i) * Dd + tid];
        __syncthreads();
        int o = tid;
        float acc = 0.f;
        #pragma unroll 8
        for (int k = 0; k < Dd; k += 4) {
            acc += WqdT[(k + 0) * Dd + o] * KS[k + 0];
            acc += WqdT[(k + 1) * Dd + o] * KS[k + 1];
            acc += WqdT[(k + 2) * Dd + o] * KS[k + 2];
            acc += WqdT[(k + 3) * Dd + o] * KS[k + 3];
        }
        Ud_ws[(b * ND + i) * Dd + o] = acc;
    }
}

// ---------------------------------------------------------------------------
// pipeline: grid B*128 (2 rows/block), 192 threads. Verified R9 main body.
// R13: theta tail (tile%4==0) computes k/v/u in ONE fused 3-stream loop
// (u via precomputed WqkT) — no second barrier, no KS LDS round-trip.
// ---------------------------------------------------------------------------
__global__ __launch_bounds__(192) void pipeline(
    const float* __restrict__ x, const float* __restrict__ W_in,
    const float* __restrict__ b_in,
    const float* __restrict__ ln1_g, const float* __restrict__ ln1_b,
    const float* __restrict__ pw1_w, const float* __restrict__ pw1_b,
    const float* __restrict__ dw_w, const float* __restrict__ dw_b,
    const float* __restrict__ bn_s, const float* __restrict__ bn_b,
    const float* __restrict__ pw2_w, const float* __restrict__ pw2_b,
    const float* __restrict__ Wavo_ws, const float* __restrict__ b_avo,
    const float* __restrict__ Ed_ws, const float* __restrict__ Ud_ws,
    const float* __restrict__ Wk_t, const float* __restrict__ Wv_t,
    const float* __restrict__ WqkT,
    float* __restrict__ x3_ws,
    float* __restrict__ Kt_ws, float* __restrict__ Vt_ws,
    float* __restrict__ Ut_ws)
{
    int blk = blockIdx.x;
    int b = blk >> 7, tile = blk & 127;
    int t0 = tile * PT, n = tile >> 5;     // delta epoch, tile-uniform (2*tile/64)
    int tid = threadIdx.x;

    __shared__ __align__(16) float XR[PT][MEL];
    __shared__ __align__(16) float XP[PT][Dd];
    __shared__ __align__(16) float ED[ND][PADD], UD[ND][PADD];
    __shared__ __align__(16) float X1[PT][Dd], X2[PT][Dd];
    __shared__ __align__(16) float LNX[PT][Dd], HG[PT][Dd];
    __shared__ float WQs[PT * ND];
    __shared__ float mv[PT][2];

    if (tid < PT * 32) {
        int r = tid >> 5, c = tid & 31;
        ((float4*)XR[r])[c] = ((const float4*)&x[((size_t)b * Tt + t0 + r) * MEL])[c];
    }
    for (int q = tid; q < ND * 48 * 2; q += 192) {
        int which = q >= ND * 48;
        int qq = which ? q - ND * 48 : q;
        int i = qq / 48, c = qq - i * 48;
        if (!which) ((float4*)ED[i])[c] = ((const float4*)&Ed_ws[(b * ND + i) * Dd])[c];
        else        ((float4*)UD[i])[c] = ((const float4*)&Ud_ws[(b * ND + i) * Dd])[c];
    }
    __syncthreads();

    int o = tid;
    // xp = x @ W_in + b_in   (K=128)
    {
        float acc[PT];
        float bb = b_in[o];
        #pragma unroll
        for (int r = 0; r < PT; r++) acc[r] = bb;
        #pragma unroll 8
        for (int k = 0; k < MEL; k += 4) {
            float w0 = W_in[(k + 0) * Dd + o], w1 = W_in[(k + 1) * Dd + o];
            float w2 = W_in[(k + 2) * Dd + o], w3 = W_in[(k + 3) * Dd + o];
            #pragma unroll
            for (int r = 0; r < PT; r++) {
                float4 xv = *(const float4*)&XR[r][k];
                acc[r] += w0 * xv.x + w1 * xv.y + w2 * xv.z + w3 * xv.w;
            }
        }
        #pragma unroll
        for (int r = 0; r < PT; r++) XP[r][tid] = acc[r];
    }
    __syncthreads();

    // delta dots: WQs[r][i] = (xp_r . u_i) * coef(n,i)   (PT*ND*8 = 64 lanes)
    if (tid < PT * 32) {
        int r = tid >> 5, i = (tid >> 3) & 3, c = tid & 7;
        float s = 0.f;
        const float* xp = XP[r];
        const float* u = UD[i];
        #pragma unroll
        for (int j = 0; j < 24; j++) s += xp[c * 24 + j] * u[c * 24 + j];
        s += __shfl_down(s, 4, 8);
        s += __shfl_down(s, 2, 8);
        s += __shfl_down(s, 1, 8);
        if (c == 0) {
            float coef = (i <= n) ? memcoef(n, i) : 0.f;
            WQs[r * ND + i] = s * coef;
        }
    }
    __syncthreads();

    // x1 = xp + 0.5 * sum_i WQs * err_i
    {
        #pragma unroll
        for (int r = 0; r < PT; r++) {
            float dout = WQs[r * ND + 0] * ED[0][tid] + WQs[r * ND + 1] * ED[1][tid]
                       + WQs[r * ND + 2] * ED[2][tid] + WQs[r * ND + 3] * ED[3][tid];
            X1[r][tid] = XP[r][tid] + 0.5f * dout;
        }
    }
    __syncthreads();

    // x2 = x1 + x1 @ Wavo + b_avo   (K=192)
    {
        float acc[PT];
        float bb = b_avo[o];
        #pragma unroll
        for (int r = 0; r < PT; r++) acc[r] = bb;
        #pragma unroll 8
        for (int k = 0; k < Dd; k += 4) {
            float w0 = Wavo_ws[(k + 0) * Dd + o], w1 = Wavo_ws[(k + 1) * Dd + o];
            float w2 = Wavo_ws[(k + 2) * Dd + o], w3 = Wavo_ws[(k + 3) * Dd + o];
            #pragma unroll
            for (int r = 0; r < PT; r++) {
                float4 xv = *(const float4*)&X1[r][k];
                acc[r] += w0 * xv.x + w1 * xv.y + w2 * xv.z + w3 * xv.w;
            }
        }
        #pragma unroll
        for (int r = 0; r < PT; r++) X2[r][tid] = X1[r][tid] + acc[r];
    }
    __syncthreads();

    // LN1 stats (PT groups of 32 lanes)
    if (tid < PT * 32) {
        int r = tid >> 5, j = tid & 31;
        float s = 0.f, sq = 0.f;
        for (int d = j; d < Dd; d += 32) { float v = X2[r][d]; s += v; sq += v * v; }
        for (int off = 16; off > 0; off >>= 1) {
            s += __shfl_down(s, off, 32); sq += __shfl_down(sq, off, 32);
        }
        if (j == 0) {
            float mean = s / Dd;
            mv[r][0] = mean;
            mv[r][1] = rsqrtf(sq / Dd - mean * mean + EPSc);
        }
    }
    __syncthreads();
    {
        float g = ln1_g[tid], bb = ln1_b[tid];
        #pragma unroll
        for (int r = 0; r < PT; r++)
            LNX[r][tid] = (X2[r][tid] - mv[r][0]) * mv[r][1] * g + bb;
    }
    __syncthreads();

    // pw1 (dual halves) + GLU + dw + bn + silu   (K=192, 2 outputs)
    {
        float aa[PT], gg[PT];
        float ba = pw1_b[o], bg = pw1_b[o + Dd];
        #pragma unroll
        for (int r = 0; r < PT; r++) { aa[r] = ba; gg[r] = bg; }
        #pragma unroll 4
        for (int k = 0; k < Dd; k += 4) {
            float wa0 = pw1_w[(k + 0) * 2 * Dd + o], wg0 = pw1_w[(k + 0) * 2 * Dd + Dd + o];
            float wa1 = pw1_w[(k + 1) * 2 * Dd + o], wg1 = pw1_w[(k + 1) * 2 * Dd + Dd + o];
            float wa2 = pw1_w[(k + 2) * 2 * Dd + o], wg2 = pw1_w[(k + 2) * 2 * Dd + Dd + o];
            float wa3 = pw1_w[(k + 3) * 2 * Dd + o], wg3 = pw1_w[(k + 3) * 2 * Dd + Dd + o];
            #pragma unroll
            for (int r = 0; r < PT; r++) {
                float4 xv = *(const float4*)&LNX[r][k];
                aa[r] += wa0 * xv.x + wa1 * xv.y + wa2 * xv.z + wa3 * xv.w;
                gg[r] += wg0 * xv.x + wg1 * xv.y + wg2 * xv.z + wg3 * xv.w;
            }
        }
        float dww = dw_w[o], dwb = dw_b[o], bns = bn_s[o], bnb = bn_b[o];
        #pragma unroll
        for (int r = 0; r < PT; r++) {
            float h = aa[r] * sigmoidf_(gg[r]);
            h = h * dww + dwb;
            h = h * bns + bnb;
            h = h * sigmoidf_(h);
            HG[r][tid] = h;
        }
    }
    __syncthreads();

    // pw2 + residual -> x3 (direct store); keep row-0 value for theta fusion
    float x3v0;
    {
        float acc[PT];
        float bb = pw2_b[o];
        #pragma unroll
        for (int r = 0; r < PT; r++) acc[r] = bb;
        #pragma unroll 8
        for (int k = 0; k < Dd; k += 4) {
            float w0 = pw2_w[(k + 0) * Dd + o], w1 = pw2_w[(k + 1) * Dd + o];
            float w2 = pw2_w[(k + 2) * Dd + o], w3 = pw2_w[(k + 3) * Dd + o];
            #pragma unroll
            for (int r = 0; r < PT; r++) {
                float4 xv = *(const float4*)&HG[r][k];
                acc[r] += w0 * xv.x + w1 * xv.y + w2 * xv.z + w3 * xv.w;
            }
        }
        #pragma unroll
        for (int r = 0; r < PT; r++)
            x3_ws[((size_t)b * Tt + t0 + r) * Dd + tid] = X2[r][tid] + acc[r];
        x3v0 = X2[0][tid] + acc[0];
    }

    // ---- theta projection for update row 8i (tile = 4i): k/v/u fused ----
    if ((tile & 3) == 0) {
        int i = tile >> 2;                 // 0..31; row 8i == t0
        float* XS = LNX[0];                // LNX free after pw1 (barrier passed)
        XS[tid] = x3v0;
        __syncthreads();

        float ak = 0.f, av = 0.f, au = 0.f;
        #pragma unroll 4
        for (int k = 0; k < Dd; k += 2) {
            float x0 = XS[k + 0], x1 = XS[k + 1];
            ak += Wk_t[(k + 0) * Dd + o] * x0 + Wk_t[(k + 1) * Dd + o] * x1;
            av += Wv_t[(k + 0) * Dd + o] * x0 + Wv_t[(k + 1) * Dd + o] * x1;
            au += WqkT[(k + 0) * Dd + o] * x0 + WqkT[(k + 1) * Dd + o] * x1;
        }
        Kt_ws[(b * NT + i) * Dd + o] = ak;
        Vt_ws[(b * NT + i) * Dd + o] = av;
        Ut_ws[(b * NT + i) * Dd + o] = au;
    }
}

// ---------------------------------------------------------------------------
// theta_solve: grid B = 8, 512 threads. (verified R9 body)
// ---------------------------------------------------------------------------
__global__ __launch_bounds__(512) void theta_solve(
    const float* __restrict__ Kt_ws, float* __restrict__ Vt_ws)
{
    int b = blockIdx.x, tid = threadIdx.x;
    __shared__ __align__(16) float K[NT][PADD];
    __shared__ float A[NT * NT], mc[NT * NT];

    for (int q = tid; q < NT * 48; q += 512) {
        int i = q / 48, c = q - i * 48;
        ((float4*)K[i])[c] = ((const float4*)&Kt_ws[(b * NT + i) * Dd])[c];
    }
    if (tid < NT) {
        int i = tid;
        float m = 0.f, pw = LRc;
        for (int nn = 0; nn < NT; nn++) {
            float v;
            if (nn < i) v = 0.f;
            else if (nn == i) { m = LRc; v = m; }
            else { pw *= ETAc; m = MDEC * m + pw; v = m; }
            mc[nn * NT + i] = v;
        }
    }
    __syncthreads();
    // A[i][m] = mc[i-1][m] * (k_i . k_m)  for m < i; else 0
    for (int p = tid; p < NT * NT; p += 512) {
        int i = p >> 5, j = p & 31;
        float s = 0.f;
        if (j < i) {
            const float4* ki = (const float4*)K[i];
            const float4* kj = (const float4*)K[j];
            float g = 0.f;
            #pragma unroll 4
            for (int kk = 0; kk < 48; kk++) g += dot4(ki[kk], kj[kk]);
            s = mc[(i - 1) * NT + j] * g;
        }
        A[p] = s;
    }
    __syncthreads();
    // per-column recurrence in registers (fully unrolled -> static indexing)
    if (tid < Dd) {
        float e[NT];
        #pragma unroll
        for (int i = 0; i < NT; i++) e[i] = Vt_ws[(b * NT + i) * Dd + tid];
        #pragma unroll
        for (int i = 1; i < NT; i++) {
            float acc = e[i];
            #pragma unroll
            for (int m = 0; m < i; m++) acc -= A[i * NT + m] * e[m];
            e[i] = acc;
        }
        #pragma unroll
        for (int i = 0; i < NT; i++) Vt_ws[(b * NT + i) * Dd + tid] = e[i];
    }
}

// ---------------------------------------------------------------------------
// retrieve: grid B*128 (RTT=2 — 1024 blocks, 4 blocks/CU; dots use 4 lanes
// per (r,i) pair so all 256 threads work). (verified R12 body)
// ---------------------------------------------------------------------------
__global__ __launch_bounds__(256) void retrieve(
    const float* __restrict__ x3_ws, const float* __restrict__ Ut_ws,
    const float* __restrict__ Et_ws, const float* __restrict__ ln2_g,
    const float* __restrict__ ln2_b, float* __restrict__ pooled)
{
    int blk = blockIdx.x, b = blk >> 7, tile = blk & 127;
    int t0 = tile * RTT, n = tile >> 2;   // theta epoch = (2*tile)/8
    int tid = threadIdx.x;

    __shared__ __align__(16) float UT[NT][PADD];
    __shared__ __align__(16) float XS[RTT][PADD];
    __shared__ float WQ[RTT * NT];
    __shared__ float mv[RTT][2];

    for (int q = tid; q < NT * 48; q += 256) {
        int i = q / 48, c = q - i * 48;
        ((float4*)UT[i])[c] = ((const float4*)&Ut_ws[(b * NT + i) * Dd])[c];
    }
    if (tid < RTT * 48) {
        int r = tid / 48, c = tid - r * 48;
        ((float4*)XS[r])[c] = ((const float4*)&x3_ws[((size_t)b * Tt + t0 + r) * Dd])[c];
    }
    __syncthreads();

    // dots: tid = r*128 + i*4 + h ; w[r][i] = (x3_r . u~_i) * coef
    {
        int r = tid >> 7, i = (tid >> 2) & 31, h = tid & 3;
        const float4* u4 = (const float4*)UT[i];
        const float4* x4 = (const float4*)XS[r];
        float s = 0.f;
        #pragma unroll
        for (int kk = h * 12; kk < h * 12 + 12; kk++) s += dot4(u4[kk], x4[kk]);
        s += __shfl_down(s, 2, 4);
        s += __shfl_down(s, 1, 4);
        if (h == 0) {
            float coef = (i <= n) ? memcoef(n, i) : 0.f;
            WQ[r * NT + i] = s * coef;
        }
    }
    __syncthreads();

    // x4 = x3 + 0.5 * sum_i WQ * err_i   (err streamed coalesced from global)
    if (tid < Dd) {
        float acc[RTT] = {};
        #pragma unroll 4
        for (int i = 0; i < NT; i++) {
            float e = Et_ws[(b * NT + i) * Dd + tid];
            #pragma unroll
            for (int r = 0; r < RTT; r++) acc[r] += WQ[r * NT + i] * e;
        }
        #pragma unroll
        for (int r = 0; r < RTT; r++) XS[r][tid] += 0.5f * acc[r];
    }
    __syncthreads();

    // LN2 stats (RTT groups of 32 lanes)
    if (tid < RTT * 32) {
        int r = tid >> 5, j = tid & 31;
        float s = 0.f, sq = 0.f;
        for (int d = j; d < Dd; d += 32) { float v = XS[r][d]; s += v; sq += v * v; }
        for (int off = 16; off > 0; off >>= 1) {
            s += __shfl_down(s, off, 32); sq += __shfl_down(sq, off, 32);
        }
        if (j == 0) {
            float mean = s / Dd;
            mv[r][0] = mean;
            mv[r][1] = rsqrtf(sq / Dd - mean * mean + EPSc);
        }
    }
    __syncthreads();

    if (tid < Dd) {
        float g = ln2_g[tid], bb = ln2_b[tid];
        float sum = 0.f;
        #pragma unroll
        for (int r = 0; r < RTT; r++)
            sum += (XS[r][tid] - mv[r][0]) * mv[r][1] * g + bb;
        atomicAdd(&pooled[b * Dd + tid], sum);
    }
}

// ---------------------------------------------------------------------------
__global__ __launch_bounds__(192) void head(
    const float* __restrict__ pooled, const float* __restrict__ Wc,
    const float* __restrict__ bc, float* __restrict__ out)
{
    int tid = threadIdx.x;
    if (tid < Bb * NCc) {
        int b = tid / NCc, c = tid - b * NCc;
        float s = 0.f;
        for (int d = 0; d < Dd; d++) s += pooled[b * Dd + d] * Wc[d * NCc + c];
        out[tid] = s * (1.0f / Tt) + bc[c];
    }
}

extern "C" void kernel_launch(void* const* d_in, const int* in_sizes, int n_in,
                              void* d_out, int out_size, void* d_ws, size_t ws_size,
                              hipStream_t stream) {
    const float* x     = (const float*)d_in[0];
    const float* W_in  = (const float*)d_in[1];
    const float* b_in  = (const float*)d_in[2];
    const float* Wv_a  = (const float*)d_in[3];
    const float* bv_a  = (const float*)d_in[4];
    const float* Wo_a  = (const float*)d_in[5];
    const float* bo_a  = (const float*)d_in[6];
    const float* ln1_g = (const float*)d_in[7];
    const float* ln1_b = (const float*)d_in[8];
    const float* pw1_w = (const float*)d_in[9];
    const float* pw1_b = (const float*)d_in[10];
    const float* dw_w  = (const float*)d_in[11];
    const float* dw_b  = (const float*)d_in[12];
    const float* bn_s  = (const float*)d_in[13];
    const float* bn_b  = (const float*)d_in[14];
    const float* pw2_w = (const float*)d_in[15];
    const float* pw2_b = (const float*)d_in[16];
    const float* Wk_t  = (const float*)d_in[17];
    const float* Wv_t  = (const float*)d_in[18];
    const float* Wq_t  = (const float*)d_in[19];
    const float* Wk_d  = (const float*)d_in[20];
    const float* Wv_d  = (const float*)d_in[21];
    const float* Wq_d  = (const float*)d_in[22];
    const float* ln2_g = (const float*)d_in[23];
    const float* ln2_b = (const float*)d_in[24];
    const float* Wc    = (const float*)d_in[25];
    const float* bc    = (const float*)d_in[26];

    float* ws = (float*)d_ws;
    size_t off = 0;
    float* x3_ws   = ws + off; off += (size_t)Bb * Tt * Dd;
    float* Kd_ws   = ws + off; off += Bb * ND * Dd;
    float* Vd_ws   = ws + off; off += Bb * ND * Dd;   // becomes err after delta_solve
    float* Ud_ws   = ws + off; off += Bb * ND * Dd;
    float* Kt_ws   = ws + off; off += Bb * NT * Dd;
    float* Vt_ws   = ws + off; off += Bb * NT * Dd;   // becomes err after theta_solve
    float* Ut_ws   = ws + off; off += Bb * NT * Dd;
    float* pooled  = ws + off; off += Bb * Dd;
    float* Wavo_ws = ws + off; off += Dd * Dd;
    float* WqtT    = ws + off; off += Dd * Dd;
    float* WqdT    = ws + off; off += Dd * Dd;
    float* WqkT    = ws + off; off += Dd * Dd;
    float* b_avo   = ws + off; off += Dd;

    prep<<<226, 192, 0, stream>>>(
        Wv_a, Wo_a, bv_a, bo_a, Wq_t, Wq_d,
        x, W_in, b_in, Wk_d, Wv_d,
        Wavo_ws, b_avo, WqtT, WqdT, Kd_ws, Vd_ws, pooled);
    delta_solve<<<88, 192, 0, stream>>>(
        WqdT, Kd_ws, Vd_ws, Ud_ws, Wk_t, WqtT, WqkT);
    pipeline<<<Bb * PTILES, 192, 0, stream>>>(
        x, W_in, b_in, ln1_g, ln1_b, pw1_w, pw1_b, dw_w, dw_b,
        bn_s, bn_b, pw2_w, pw2_b, Wavo_ws, b_avo, Vd_ws, Ud_ws,
        Wk_t, Wv_t, WqkT, x3_ws, Kt_ws, Vt_ws, Ut_ws);
    theta_solve<<<Bb, 512, 0, stream>>>(Kt_ws, Vt_ws);
    retrieve<<<Bb * 128, 256, 0, stream>>>(
        x3_ws, Ut_ws, Vt_ws, ln2_g, ln2_b, pooled);
    head<<<1, 192, 0, stream>>>(pooled, Wc, bc, (float*)d_out);
}

// Round 14
// 188.801 us; speedup vs baseline: 1.0423x; 1.0423x over previous
//
#include <hip/hip_runtime.h>
#include <math.h>

#define Bb 8
#define Tt 256
#define MEL 128
#define Dd 192
#define NCc 20
#define ND 4                  // delta ranks (updates at t%64==0)
#define NT 32                 // theta ranks (updates at t%8==0)
#define ETAc 0.9f
#define LRc 0.1f
#define MDEC 0.99f            // 1 - ALPHA
#define EPSc 1e-5f
#define PT 2                  // pipeline rows per block (best measured structure)
#define PTILES 128            // Tt/PT
#define RTT 4                 // retrieve rows per block
#define PADD 196              // padded LDS row (196%4==0, 196%32==4 -> <=4-way)

__device__ __forceinline__ float sigmoidf_(float x) {
    return 1.0f / (1.0f + __expf(-x));
}

// coefficient of (k_i err_i^T) in M_n, valid for i<=n
__device__ __forceinline__ float memcoef(int n, int i) {
    float m = LRc, pw = LRc;
    for (int nn = i + 1; nn <= n; nn++) { pw *= ETAc; m = MDEC * m + pw; }
    return m;
}

__device__ __forceinline__ float dot4(float4 a, float4 b) {
    return a.x * b.x + a.y * b.y + a.z * b.z + a.w * b.w;
}

// ---------------------------------------------------------------------------
// prep: grid 178 x 192 — everything parallel & coalesced. (verified R9 body)
// ---------------------------------------------------------------------------
__global__ __launch_bounds__(192) void prep(
    const float* __restrict__ Wv_a, const float* __restrict__ Wo_a,
    const float* __restrict__ bv_a, const float* __restrict__ bo_a,
    const float* __restrict__ Wq_t, const float* __restrict__ Wq_d,
    const float* __restrict__ x, const float* __restrict__ W_in,
    const float* __restrict__ b_in, const float* __restrict__ Wk_d,
    const float* __restrict__ Wv_d,
    float* __restrict__ Wavo_ws, float* __restrict__ b_avo,
    float* __restrict__ WqtT, float* __restrict__ WqdT,
    float* __restrict__ Kd_ws, float* __restrict__ Vd_ws,
    float* __restrict__ pooled)
{
    __shared__ __align__(16) float smem[768];
    int blk = blockIdx.x, tid = threadIdx.x;

    if (blk < 48) {                               // Wavo: 4 rows per block
        int m0 = blk * 4;
        for (int q = tid; q < 4 * Dd; q += 192) smem[q] = Wv_a[m0 * Dd + q];
        __syncthreads();
        int o = tid;
        float a0 = 0.f, a1 = 0.f, a2 = 0.f, a3 = 0.f;
        #pragma unroll 4
        for (int k = 0; k < Dd; k += 2) {
            float w0 = Wo_a[(k + 0) * Dd + o], w1 = Wo_a[(k + 1) * Dd + o];
            a0 += w0 * smem[0 * Dd + k] + w1 * smem[0 * Dd + k + 1];
            a1 += w0 * smem[1 * Dd + k] + w1 * smem[1 * Dd + k + 1];
            a2 += w0 * smem[2 * Dd + k] + w1 * smem[2 * Dd + k + 1];
            a3 += w0 * smem[3 * Dd + k] + w1 * smem[3 * Dd + k + 1];
        }
        Wavo_ws[(m0 + 0) * Dd + o] = a0;
        Wavo_ws[(m0 + 1) * Dd + o] = a1;
        Wavo_ws[(m0 + 2) * Dd + o] = a2;
        Wavo_ws[(m0 + 3) * Dd + o] = a3;
        return;
    }
    if (blk == 48) {                              // b_avo
        int o = tid;
        float s = bo_a[o];
        #pragma unroll 4
        for (int m = 0; m < Dd; m++) s += bv_a[m] * Wo_a[m * Dd + o];
        b_avo[o] = s;
        return;
    }
    if (blk < 97) {                               // WqtT[e][o] = Wq_t[o][e]
        int r0 = 4 * (blk - 49);
        float4 v;
        v.x = Wq_t[(r0 + 0) * Dd + tid];
        v.y = Wq_t[(r0 + 1) * Dd + tid];
        v.z = Wq_t[(r0 + 2) * Dd + tid];
        v.w = Wq_t[(r0 + 3) * Dd + tid];
        *(float4*)&WqtT[tid * Dd + r0] = v;
        return;
    }
    if (blk < 145) {                              // WqdT[e][o] = Wq_d[o][e]
        int r0 = 4 * (blk - 97);
        float4 v;
        v.x = Wq_d[(r0 + 0) * Dd + tid];
        v.y = Wq_d[(r0 + 1) * Dd + tid];
        v.z = Wq_d[(r0 + 2) * Dd + tid];
        v.w = Wq_d[(r0 + 3) * Dd + tid];
        *(float4*)&WqdT[tid * Dd + r0] = v;
        return;
    }
    if (blk == 177) {                             // zero pooled
        for (int q = tid; q < Bb * Dd; q += 192) pooled[q] = 0.f;
        return;
    }

    // ---- delta k/v for (b,i) ----
    int q = blk - 145;
    int b = q >> 2, i = q & 3;
    float* XR = smem;              // [128]
    float* XP = smem + 128;        // [192]
    if (tid < 128) XR[tid] = x[((size_t)b * Tt + 64 * i) * MEL + tid];
    __syncthreads();
    {
        int o = tid;
        float acc = b_in[o];
        #pragma unroll 8
        for (int k = 0; k < MEL; k += 4) {
            acc += W_in[(k + 0) * Dd + o] * XR[k + 0];
            acc += W_in[(k + 1) * Dd + o] * XR[k + 1];
            acc += W_in[(k + 2) * Dd + o] * XR[k + 2];
            acc += W_in[(k + 3) * Dd + o] * XR[k + 3];
        }
        XP[o] = acc;
    }
    __syncthreads();
    {
        int o = tid;
        float ak = 0.f, av = 0.f;
        #pragma unroll 4
        for (int k = 0; k < Dd; k += 4) {
            float x0 = XP[k + 0], x1 = XP[k + 1], x2 = XP[k + 2], x3 = XP[k + 3];
            ak += Wk_d[(k + 0) * Dd + o] * x0 + Wk_d[(k + 1) * Dd + o] * x1
                + Wk_d[(k + 2) * Dd + o] * x2 + Wk_d[(k + 3) * Dd + o] * x3;
            av += Wv_d[(k + 0) * Dd + o] * x0 + Wv_d[(k + 1) * Dd + o] * x1
                + Wv_d[(k + 2) * Dd + o] * x2 + Wv_d[(k + 3) * Dd + o] * x3;
        }
        Kd_ws[(b * ND + i) * Dd + o] = ak;
        Vd_ws[(b * ND + i) * Dd + o] = av;
    }
}

// ---------------------------------------------------------------------------
// delta_solve: grid B*5 = 40. (verified R9 body)
// ---------------------------------------------------------------------------
__global__ __launch_bounds__(192) void delta_solve(
    const float* __restrict__ WqdT, const float* __restrict__ Kd_ws,
    float* __restrict__ Vd_ws, float* __restrict__ Ud_ws)
{
    int blk = blockIdx.x, b = blk / 5, role = blk % 5, tid = threadIdx.x;
    if (role == 0) {
        __shared__ __align__(16) float K4[ND][Dd], V4[ND][Dd];
        __shared__ float G[16], mc[16];
        for (int q = tid; q < ND * 48; q += 192) {
            int i = q / 48, c = q - i * 48;
            ((float4*)K4[i])[c] = ((const float4*)&Kd_ws[(b * ND + i) * Dd])[c];
            ((float4*)V4[i])[c] = ((const float4*)&Vd_ws[(b * ND + i) * Dd])[c];
        }
        __syncthreads();
        if (tid < 128) {                       // pair p = tid>>3, lane c = tid&7
            int p = tid >> 3, c = tid & 7;
            int i = p >> 2, j = p & 3;
            float s = 0.f;
            #pragma unroll
            for (int d = c * 24; d < c * 24 + 24; d++) s += K4[i][d] * K4[j][d];
            s += __shfl_down(s, 4, 8);
            s += __shfl_down(s, 2, 8);
            s += __shfl_down(s, 1, 8);
            if (c == 0) G[p] = s;
        }
        if (tid < 16) {
            int i = tid >> 2, j = tid & 3;
            mc[tid] = (j <= i) ? memcoef(i, j) : 0.f;   // mc[n=i][i=j]
        }
        __syncthreads();
        for (int i = 1; i < ND; i++) {
            float acc = V4[i][tid];
            for (int m = 0; m < i; m++)
                acc -= mc[(i - 1) * ND + m] * G[i * ND + m] * V4[m][tid];
            V4[i][tid] = acc;        // writes row i; others read rows < i only
            __syncthreads();
        }
        for (int i = 0; i < ND; i++) Vd_ws[(b * ND + i) * Dd + tid] = V4[i][tid];
    } else {
        __shared__ float KS[Dd];
        int i = role - 1;
        KS[tid] = Kd_ws[(b * ND + i) * Dd + tid];
        __syncthreads();
        int o = tid;
        float acc = 0.f;
        #pragma unroll 8
        for (int k = 0; k < Dd; k += 4) {
            acc += WqdT[(k + 0) * Dd + o] * KS[k + 0];
            acc += WqdT[(k + 1) * Dd + o] * KS[k + 1];
            acc += WqdT[(k + 2) * Dd + o] * KS[k + 2];
            acc += WqdT[(k + 3) * Dd + o] * KS[k + 3];
        }
        Ud_ws[(b * ND + i) * Dd + o] = acc;
    }
}

// ---------------------------------------------------------------------------
// pipeline: grid B*128 (2 rows/block), 192 threads. Verified R9 body
// (189.2 µs): theta tail (tile%4==0) computes k/v/u for update row 8i.
// ---------------------------------------------------------------------------
__global__ __launch_bounds__(192) void pipeline(
    const float* __restrict__ x, const float* __restrict__ W_in,
    const float* __restrict__ b_in,
    const float* __restrict__ ln1_g, const float* __restrict__ ln1_b,
    const float* __restrict__ pw1_w, const float* __restrict__ pw1_b,
    const float* __restrict__ dw_w, const float* __restrict__ dw_b,
    const float* __restrict__ bn_s, const float* __restrict__ bn_b,
    const float* __restrict__ pw2_w, const float* __restrict__ pw2_b,
    const float* __restrict__ Wavo_ws, const float* __restrict__ b_avo,
    const float* __restrict__ Ed_ws, const float* __restrict__ Ud_ws,
    const float* __restrict__ Wk_t, const float* __restrict__ Wv_t,
    const float* __restrict__ WqtT,
    float* __restrict__ x3_ws,
    float* __restrict__ Kt_ws, float* __restrict__ Vt_ws,
    float* __restrict__ Ut_ws)
{
    int blk = blockIdx.x;
    int b = blk >> 7, tile = blk & 127;
    int t0 = tile * PT, n = tile >> 5;     // delta epoch, tile-uniform (2*tile/64)
    int tid = threadIdx.x;

    __shared__ __align__(16) float XR[PT][MEL];
    __shared__ __align__(16) float XP[PT][Dd];
    __shared__ __align__(16) float ED[ND][PADD], UD[ND][PADD];
    __shared__ __align__(16) float X1[PT][Dd], X2[PT][Dd];
    __shared__ __align__(16) float LNX[PT][Dd], HG[PT][Dd];
    __shared__ float WQs[PT * ND];
    __shared__ float mv[PT][2];

    if (tid < PT * 32) {
        int r = tid >> 5, c = tid & 31;
        ((float4*)XR[r])[c] = ((const float4*)&x[((size_t)b * Tt + t0 + r) * MEL])[c];
    }
    for (int q = tid; q < ND * 48 * 2; q += 192) {
        int which = q >= ND * 48;
        int qq = which ? q - ND * 48 : q;
        int i = qq / 48, c = qq - i * 48;
        if (!which) ((float4*)ED[i])[c] = ((const float4*)&Ed_ws[(b * ND + i) * Dd])[c];
        else        ((float4*)UD[i])[c] = ((const float4*)&Ud_ws[(b * ND + i) * Dd])[c];
    }
    __syncthreads();

    int o = tid;
    // xp = x @ W_in + b_in   (K=128)
    {
        float acc[PT];
        float bb = b_in[o];
        #pragma unroll
        for (int r = 0; r < PT; r++) acc[r] = bb;
        #pragma unroll 8
        for (int k = 0; k < MEL; k += 4) {
            float w0 = W_in[(k + 0) * Dd + o], w1 = W_in[(k + 1) * Dd + o];
            float w2 = W_in[(k + 2) * Dd + o], w3 = W_in[(k + 3) * Dd + o];
            #pragma unroll
            for (int r = 0; r < PT; r++) {
                float4 xv = *(const float4*)&XR[r][k];
                acc[r] += w0 * xv.x + w1 * xv.y + w2 * xv.z + w3 * xv.w;
            }
        }
        #pragma unroll
        for (int r = 0; r < PT; r++) XP[r][tid] = acc[r];
    }
    __syncthreads();

    // delta dots: WQs[r][i] = (xp_r . u_i) * coef(n,i)   (PT*ND*8 = 64 lanes)
    if (tid < PT * 32) {
        int r = tid >> 5, i = (tid >> 3) & 3, c = tid & 7;
        float s = 0.f;
        const float* xp = XP[r];
        const float* u = UD[i];
        #pragma unroll
        for (int j = 0; j < 24; j++) s += xp[c * 24 + j] * u[c * 24 + j];
        s += __shfl_down(s, 4, 8);
        s += __shfl_down(s, 2, 8);
        s += __shfl_down(s, 1, 8);
        if (c == 0) {
            float coef = (i <= n) ? memcoef(n, i) : 0.f;
            WQs[r * ND + i] = s * coef;
        }
    }
    __syncthreads();

    // x1 = xp + 0.5 * sum_i WQs * err_i
    {
        #pragma unroll
        for (int r = 0; r < PT; r++) {
            float dout = WQs[r * ND + 0] * ED[0][tid] + WQs[r * ND + 1] * ED[1][tid]
                       + WQs[r * ND + 2] * ED[2][tid] + WQs[r * ND + 3] * ED[3][tid];
            X1[r][tid] = XP[r][tid] + 0.5f * dout;
        }
    }
    __syncthreads();

    // x2 = x1 + x1 @ Wavo + b_avo   (K=192)
    {
        float acc[PT];
        float bb = b_avo[o];
        #pragma unroll
        for (int r = 0; r < PT; r++) acc[r] = bb;
        #pragma unroll 8
        for (int k = 0; k < Dd; k += 4) {
            float w0 = Wavo_ws[(k + 0) * Dd + o], w1 = Wavo_ws[(k + 1) * Dd + o];
            float w2 = Wavo_ws[(k + 2) * Dd + o], w3 = Wavo_ws[(k + 3) * Dd + o];
            #pragma unroll
            for (int r = 0; r < PT; r++) {
                float4 xv = *(const float4*)&X1[r][k];
                acc[r] += w0 * xv.x + w1 * xv.y + w2 * xv.z + w3 * xv.w;
            }
        }
        #pragma unroll
        for (int r = 0; r < PT; r++) X2[r][tid] = X1[r][tid] + acc[r];
    }
    __syncthreads();

    // LN1 stats (PT groups of 32 lanes)
    if (tid < PT * 32) {
        int r = tid >> 5, j = tid & 31;
        float s = 0.f, sq = 0.f;
        for (int d = j; d < Dd; d += 32) { float v = X2[r][d]; s += v; sq += v * v; }
        for (int off = 16; off > 0; off >>= 1) {
            s += __shfl_down(s, off, 32); sq += __shfl_down(sq, off, 32);
        }
        if (j == 0) {
            float mean = s / Dd;
            mv[r][0] = mean;
            mv[r][1] = rsqrtf(sq / Dd - mean * mean + EPSc);
        }
    }
    __syncthreads();
    {
        float g = ln1_g[tid], bb = ln1_b[tid];
        #pragma unroll
        for (int r = 0; r < PT; r++)
            LNX[r][tid] = (X2[r][tid] - mv[r][0]) * mv[r][1] * g + bb;
    }
    __syncthreads();

    // pw1 (dual halves) + GLU + dw + bn + silu   (K=192, 2 outputs)
    {
        float aa[PT], gg[PT];
        float ba = pw1_b[o], bg = pw1_b[o + Dd];
        #pragma unroll
        for (int r = 0; r < PT; r++) { aa[r] = ba; gg[r] = bg; }
        #pragma unroll 4
        for (int k = 0; k < Dd; k += 4) {
            float wa0 = pw1_w[(k + 0) * 2 * Dd + o], wg0 = pw1_w[(k + 0) * 2 * Dd + Dd + o];
            float wa1 = pw1_w[(k + 1) * 2 * Dd + o], wg1 = pw1_w[(k + 1) * 2 * Dd + Dd + o];
            float wa2 = pw1_w[(k + 2) * 2 * Dd + o], wg2 = pw1_w[(k + 2) * 2 * Dd + Dd + o];
            float wa3 = pw1_w[(k + 3) * 2 * Dd + o], wg3 = pw1_w[(k + 3) * 2 * Dd + Dd + o];
            #pragma unroll
            for (int r = 0; r < PT; r++) {
                float4 xv = *(const float4*)&LNX[r][k];
                aa[r] += wa0 * xv.x + wa1 * xv.y + wa2 * xv.z + wa3 * xv.w;
                gg[r] += wg0 * xv.x + wg1 * xv.y + wg2 * xv.z + wg3 * xv.w;
            }
        }
        float dww = dw_w[o], dwb = dw_b[o], bns = bn_s[o], bnb = bn_b[o];
        #pragma unroll
        for (int r = 0; r < PT; r++) {
            float h = aa[r] * sigmoidf_(gg[r]);
            h = h * dww + dwb;
            h = h * bns + bnb;
            h = h * sigmoidf_(h);
            HG[r][tid] = h;
        }
    }
    __syncthreads();

    // pw2 + residual -> x3 (direct store); keep row-0 value for theta fusion
    float x3v0;
    {
        float acc[PT];
        float bb = pw2_b[o];
        #pragma unroll
        for (int r = 0; r < PT; r++) acc[r] = bb;
        #pragma unroll 8
        for (int k = 0; k < Dd; k += 4) {
            float w0 = pw2_w[(k + 0) * Dd + o], w1 = pw2_w[(k + 1) * Dd + o];
            float w2 = pw2_w[(k + 2) * Dd + o], w3 = pw2_w[(k + 3) * Dd + o];
            #pragma unroll
            for (int r = 0; r < PT; r++) {
                float4 xv = *(const float4*)&HG[r][k];
                acc[r] += w0 * xv.x + w1 * xv.y + w2 * xv.z + w3 * xv.w;
            }
        }
        #pragma unroll
        for (int r = 0; r < PT; r++)
            x3_ws[((size_t)b * Tt + t0 + r) * Dd + tid] = X2[r][tid] + acc[r];
        x3v0 = X2[0][tid] + acc[0];
    }

    // ---- theta projection for update row 8i (tile = 4i): k, v, u ----
    if ((tile & 3) == 0) {
        int i = tile >> 2;                 // 0..31; row 8i == t0
        float* XS = LNX[0];                // LNX free after pw1 (barrier passed)
        float* KS = LNX[1];
        XS[tid] = x3v0;
        __syncthreads();

        float ak = 0.f, av = 0.f;
        #pragma unroll 4
        for (int k = 0; k < Dd; k += 4) {
            float x0 = XS[k + 0], x1 = XS[k + 1], x2 = XS[k + 2], x3 = XS[k + 3];
            ak += Wk_t[(k + 0) * Dd + o] * x0 + Wk_t[(k + 1) * Dd + o] * x1
                + Wk_t[(k + 2) * Dd + o] * x2 + Wk_t[(k + 3) * Dd + o] * x3;
            av += Wv_t[(k + 0) * Dd + o] * x0 + Wv_t[(k + 1) * Dd + o] * x1
                + Wv_t[(k + 2) * Dd + o] * x2 + Wv_t[(k + 3) * Dd + o] * x3;
        }
        Kt_ws[(b * NT + i) * Dd + o] = ak;
        Vt_ws[(b * NT + i) * Dd + o] = av;
        KS[o] = ak;
        __syncthreads();

        float au = 0.f;
        #pragma unroll 8
        for (int k = 0; k < Dd; k += 4) {
            au += WqtT[(k + 0) * Dd + o] * KS[k + 0];
            au += WqtT[(k + 1) * Dd + o] * KS[k + 1];
            au += WqtT[(k + 2) * Dd + o] * KS[k + 2];
            au += WqtT[(k + 3) * Dd + o] * KS[k + 3];
        }
        Ut_ws[(b * NT + i) * Dd + o] = au;
    }
}

// ---------------------------------------------------------------------------
// theta_solve: grid B = 8, 512 threads. (verified R9 body)
// ---------------------------------------------------------------------------
__global__ __launch_bounds__(512) void theta_solve(
    const float* __restrict__ Kt_ws, float* __restrict__ Vt_ws)
{
    int b = blockIdx.x, tid = threadIdx.x;
    __shared__ __align__(16) float K[NT][PADD];
    __shared__ float A[NT * NT], mc[NT * NT];

    for (int q = tid; q < NT * 48; q += 512) {
        int i = q / 48, c = q - i * 48;
        ((float4*)K[i])[c] = ((const float4*)&Kt_ws[(b * NT + i) * Dd])[c];
    }
    if (tid < NT) {
        int i = tid;
        float m = 0.f, pw = LRc;
        for (int nn = 0; nn < NT; nn++) {
            float v;
            if (nn < i) v = 0.f;
            else if (nn == i) { m = LRc; v = m; }
            else { pw *= ETAc; m = MDEC * m + pw; v = m; }
            mc[nn * NT + i] = v;
        }
    }
    __syncthreads();
    // A[i][m] = mc[i-1][m] * (k_i . k_m)  for m < i; else 0
    for (int p = tid; p < NT * NT; p += 512) {
        int i = p >> 5, j = p & 31;
        float s = 0.f;
        if (j < i) {
            const float4* ki = (const float4*)K[i];
            const float4* kj = (const float4*)K[j];
            float g = 0.f;
            #pragma unroll 4
            for (int kk = 0; kk < 48; kk++) g += dot4(ki[kk], kj[kk]);
            s = mc[(i - 1) * NT + j] * g;
        }
        A[p] = s;
    }
    __syncthreads();
    // per-column recurrence in registers (fully unrolled -> static indexing)
    if (tid < Dd) {
        float e[NT];
        #pragma unroll
        for (int i = 0; i < NT; i++) e[i] = Vt_ws[(b * NT + i) * Dd + tid];
        #pragma unroll
        for (int i = 1; i < NT; i++) {
            float acc = e[i];
            #pragma unroll
            for (int m = 0; m < i; m++) acc -= A[i * NT + m] * e[m];
            e[i] = acc;
        }
        #pragma unroll
        for (int i = 0; i < NT; i++) Vt_ws[(b * NT + i) * Dd + tid] = e[i];
    }
}

// ---------------------------------------------------------------------------
// retrieve: grid B*64 (4 rows/block), 256 threads; dots use 2 lanes per
// (r,i) pair so all 256 threads participate. (verified R9 body)
// ---------------------------------------------------------------------------
__global__ __launch_bounds__(256) void retrieve(
    const float* __restrict__ x3_ws, const float* __restrict__ Ut_ws,
    const float* __restrict__ Et_ws, const float* __restrict__ ln2_g,
    const float* __restrict__ ln2_b, float* __restrict__ pooled)
{
    int blk = blockIdx.x, b = blk >> 5, tile = blk & 63;
    int t0 = tile * RTT, n = tile >> 1;   // theta epoch = (4*tile)/8
    int tid = threadIdx.x;

    __shared__ __align__(16) float UT[NT][PADD];
    __shared__ __align__(16) float XS[RTT][PADD];
    __shared__ float WQ[RTT * NT];
    __shared__ float mv[RTT][2];

    b = blk >> 6;                        // correct batch decode (64 tiles/batch)

    for (int q = tid; q < NT * 48; q += 256) {
        int i = q / 48, c = q - i * 48;
        ((float4*)UT[i])[c] = ((const float4*)&Ut_ws[(b * NT + i) * Dd])[c];
    }
    for (int q = tid; q < RTT * 48; q += 256) {
        int r = q / 48, c = q - r * 48;
        ((float4*)XS[r])[c] = ((const float4*)&x3_ws[((size_t)b * Tt + t0 + r) * Dd])[c];
    }
    __syncthreads();

    // dots: tid = r*64 + i*2 + h ; w[r][i] = (x3_r . u~_i) * coef
    {
        int r = tid >> 6, i = (tid >> 1) & 31, h = tid & 1;
        const float4* u4 = (const float4*)UT[i];
        const float4* x4 = (const float4*)XS[r];
        float s = 0.f;
        #pragma unroll 8
        for (int kk = h * 24; kk < h * 24 + 24; kk++) s += dot4(u4[kk], x4[kk]);
        s += __shfl_down(s, 1, 2);
        if (h == 0) {
            float coef = (i <= n) ? memcoef(n, i) : 0.f;
            WQ[r * NT + i] = s * coef;
        }
    }
    __syncthreads();

    // x4 = x3 + 0.5 * sum_i WQ * err_i   (err streamed coalesced from global)
    if (tid < Dd) {
        float acc[RTT] = {};
        #pragma unroll 4
        for (int i = 0; i < NT; i++) {
            float e = Et_ws[(b * NT + i) * Dd + tid];
            #pragma unroll
            for (int r = 0; r < RTT; r++) acc[r] += WQ[r * NT + i] * e;
        }
        #pragma unroll
        for (int r = 0; r < RTT; r++) XS[r][tid] += 0.5f * acc[r];
    }
    __syncthreads();

    // LN2 stats (RTT groups of 32 lanes)
    if (tid < RTT * 32) {
        int r = tid >> 5, j = tid & 31;
        float s = 0.f, sq = 0.f;
        for (int d = j; d < Dd; d += 32) { float v = XS[r][d]; s += v; sq += v * v; }
        for (int off = 16; off > 0; off >>= 1) {
            s += __shfl_down(s, off, 32); sq += __shfl_down(sq, off, 32);
        }
        if (j == 0) {
            float mean = s / Dd;
            mv[r][0] = mean;
            mv[r][1] = rsqrtf(sq / Dd - mean * mean + EPSc);
        }
    }
    __syncthreads();

    if (tid < Dd) {
        float g = ln2_g[tid], bb = ln2_b[tid];
        float sum = 0.f;
        #pragma unroll
        for (int r = 0; r < RTT; r++)
            sum += (XS[r][tid] - mv[r][0]) * mv[r][1] * g + bb;
        atomicAdd(&pooled[b * Dd + tid], sum);
    }
}

// ---------------------------------------------------------------------------
__global__ __launch_bounds__(192) void head(
    const float* __restrict__ pooled, const float* __restrict__ Wc,
    const float* __restrict__ bc, float* __restrict__ out)
{
    int tid = threadIdx.x;
    if (tid < Bb * NCc) {
        int b = tid / NCc, c = tid - b * NCc;
        float s = 0.f;
        for (int d = 0; d < Dd; d++) s += pooled[b * Dd + d] * Wc[d * NCc + c];
        out[tid] = s * (1.0f / Tt) + bc[c];
    }
}

extern "C" void kernel_launch(void* const* d_in, const int* in_sizes, int n_in,
                              void* d_out, int out_size, void* d_ws, size_t ws_size,
                              hipStream_t stream) {
    const float* x     = (const float*)d_in[0];
    const float* W_in  = (const float*)d_in[1];
    const float* b_in  = (const float*)d_in[2];
    const float* Wv_a  = (const float*)d_in[3];
    const float* bv_a  = (const float*)d_in[4];
    const float* Wo_a  = (const float*)d_in[5];
    const float* bo_a  = (const float*)d_in[6];
    const float* ln1_g = (const float*)d_in[7];
    const float* ln1_b = (const float*)d_in[8];
    const float* pw1_w = (const float*)d_in[9];
    const float* pw1_b = (const float*)d_in[10];
    const float* dw_w  = (const float*)d_in[11];
    const float* dw_b  = (const float*)d_in[12];
    const float* bn_s  = (const float*)d_in[13];
    const float* bn_b  = (const float*)d_in[14];
    const float* pw2_w = (const float*)d_in[15];
    const float* pw2_b = (const float*)d_in[16];
    const float* Wk_t  = (const float*)d_in[17];
    const float* Wv_t  = (const float*)d_in[18];
    const float* Wq_t  = (const float*)d_in[19];
    const float* Wk_d  = (const float*)d_in[20];
    const float* Wv_d  = (const float*)d_in[21];
    const float* Wq_d  = (const float*)d_in[22];
    const float* ln2_g = (const float*)d_in[23];
    const float* ln2_b = (const float*)d_in[24];
    const float* Wc    = (const float*)d_in[25];
    const float* bc    = (const float*)d_in[26];

    float* ws = (float*)d_ws;
    size_t off = 0;
    float* x3_ws   = ws + off; off += (size_t)Bb * Tt * Dd;
    float* Kd_ws   = ws + off; off += Bb * ND * Dd;
    float* Vd_ws   = ws + off; off += Bb * ND * Dd;   // becomes err after delta_solve
    float* Ud_ws   = ws + off; off += Bb * ND * Dd;
    float* Kt_ws   = ws + off; off += Bb * NT * Dd;
    float* Vt_ws   = ws + off; off += Bb * NT * Dd;   // becomes err after theta_solve
    float* Ut_ws   = ws + off; off += Bb * NT * Dd;
    float* pooled  = ws + off; off += Bb * Dd;
    float* Wavo_ws = ws + off; off += Dd * Dd;
    float* WqtT    = ws + off; off += Dd * Dd;
    float* WqdT    = ws + off; off += Dd * Dd;
    float* b_avo   = ws + off; off += Dd;

    prep<<<178, 192, 0, stream>>>(
        Wv_a, Wo_a, bv_a, bo_a, Wq_t, Wq_d,
        x, W_in, b_in, Wk_d, Wv_d,
        Wavo_ws, b_avo, WqtT, WqdT, Kd_ws, Vd_ws, pooled);
    delta_solve<<<Bb * 5, 192, 0, stream>>>(WqdT, Kd_ws, Vd_ws, Ud_ws);
    pipeline<<<Bb * PTILES, 192, 0, stream>>>(
        x, W_in, b_in, ln1_g, ln1_b, pw1_w, pw1_b, dw_w, dw_b,
        bn_s, bn_b, pw2_w, pw2_b, Wavo_ws, b_avo, Vd_ws, Ud_ws,
        Wk_t, Wv_t, WqtT, x3_ws, Kt_ws, Vt_ws, Ut_ws);
    theta_solve<<<Bb, 512, 0, stream>>>(Kt_ws, Vt_ws);
    retrieve<<<Bb * 64, 256, 0, stream>>>(
        x3_ws, Ut_ws, Vt_ws, ln2_g, ln2_b, pooled);
    head<<<1, 192, 0, stream>>>(pooled, Wc, bc, (float*)d_out);
}